// Round 2
// baseline (380.134 us; speedup 1.0000x reference)
//
#include <hip/hip_runtime.h>
#include <hip/hip_bf16.h>

typedef __attribute__((ext_vector_type(8))) short bf16x8;
typedef __attribute__((ext_vector_type(4))) float f32x4;

#define IN 128
#define OUT 128
#define NB 8192
#define NCH 129
#define WB_CHUNK (OUT * IN)           // 16384 elements per chunk
#define SWZ(j) ((((j) >> 2) & 7) << 2)

static __device__ __forceinline__ unsigned short f2bf(float v) {
    unsigned u = __builtin_bit_cast(unsigned, v);
    unsigned r = (u + 0x7FFFu + ((u >> 16) & 1u)) >> 16;   // RNE
    return (unsigned short)r;
}

// ---- prep: WB[129][o][j] bf16 (chunk i: lc_w[o,pos(i,j)], diag=0; chunk 128: w1*scale)
// ---- plus bias[o] = sum_j translation[j]*w1[o,j]
__global__ __launch_bounds__(256) void prep_kernel(
    const float* __restrict__ lcw, const float* __restrict__ w1,
    const float* __restrict__ sc, const float* __restrict__ tr,
    __hip_bfloat16* __restrict__ WB, float* __restrict__ bias)
{
    if (blockIdx.x < 1032) {
        size_t idx = (size_t)blockIdx.x * 2048 + (size_t)threadIdx.x * 8;
        int c   = (int)(idx >> 14);
        int rem = (int)(idx & 16383);
        int o   = rem >> 7;
        int j0  = rem & 127;
        bf16x8 v;
        if (c < 128) {
            const float* lr = lcw + (size_t)o * 16256 + (size_t)c * 127;
            #pragma unroll
            for (int e = 0; e < 8; ++e) {
                int j = j0 + e;
                float f = (j == c) ? 0.f : lr[(j < c) ? j : (j - 1)];
                v[e] = (short)f2bf(f);
            }
        } else {
            #pragma unroll
            for (int e = 0; e < 8; ++e) {
                int j = j0 + e;
                v[e] = (short)f2bf(w1[o * 128 + j] * sc[j]);
            }
        }
        *(bf16x8*)(WB + idx) = v;
    } else {
        // bias[o] = sum_j tr[j]*w1[o,j] — wave-parallel, coalesced 8B/lane
        const int lane = threadIdx.x & 63;
        const int wv   = threadIdx.x >> 6;         // 0..3
        const float2 t2 = *(const float2*)(tr + lane * 2);
        for (int o = wv; o < 128; o += 4) {
            const float2 w2 = *(const float2*)(w1 + o * 128 + lane * 2);
            float s = t2.x * w2.x + t2.y * w2.y;
            #pragma unroll
            for (int m = 1; m < 64; m <<= 1) s += __shfl_xor(s, m);
            if (lane == 0) bias[o] = s;
        }
    }
}

// ---- main GEMM: (64*KSPLIT) WGs (64 M-tiles x KSPLIT K-splits), 512 thr = 8 waves (2M x 4N)
template<int KSPLIT>
__global__ __launch_bounds__(512, 4) void lc_gemm(
    const float* __restrict__ x, const float* __restrict__ sc, const float* __restrict__ tr,
    const __hip_bfloat16* __restrict__ WB, float* __restrict__ parts)
{
    __shared__ float XT[IN * 128];    // XT[j][row ^ SWZ(j)] = x_scaled, 64 KB

    const int tid = threadIdx.x;
    const int bid = blockIdx.x;
    const int mt  = bid / KSPLIT;
    const int kq  = bid % KSPLIT;     // == XCD id for KSPLIT=8
    const int row0 = mt << 7;

    {   // stage + transpose + scale/translate
        const int jj  = (tid & 31) << 2;
        const int swz = SWZ(jj);
        const float4 s4 = *(const float4*)(sc + jj);
        const float4 t4 = *(const float4*)(tr + jj);
        const float i0 = 1.f / s4.x, i1 = 1.f / s4.y, i2 = 1.f / s4.z, i3 = 1.f / s4.w;
        const int rb0 = tid >> 5;
        #pragma unroll
        for (int it = 0; it < 8; ++it) {
            const int r = rb0 + (it << 4);
            const float4 xv = *(const float4*)(x + (size_t)(row0 + r) * IN + jj);
            const int rs = r ^ swz;
            XT[(jj + 0) * 128 + rs] = (xv.x - t4.x) * i0;
            XT[(jj + 1) * 128 + rs] = (xv.y - t4.y) * i1;
            XT[(jj + 2) * 128 + rs] = (xv.z - t4.z) * i2;
            XT[(jj + 3) * 128 + rs] = (xv.w - t4.w) * i3;
        }
    }
    __syncthreads();

    const int lane = tid & 63;
    const int wv = tid >> 6;
    const int wm = wv >> 2;       // 0..1 : 64-row half
    const int wn = wv & 3;        // 0..3 : 32-col group
    const int cl = lane & 15;
    const int kg = lane >> 4;

    // A fragments: constant for the whole kernel (bf16 of scaled x)
    bf16x8 a[4][4];
    #pragma unroll
    for (int rb = 0; rb < 4; ++rb) {
        const int row = wm * 64 + rb * 16 + cl;
        #pragma unroll
        for (int s = 0; s < 4; ++s) {
            const int j0 = s * 32 + kg * 8;
            bf16x8 av;
            #pragma unroll
            for (int e = 0; e < 8; ++e) {
                const int j = j0 + e;
                av[e] = (short)f2bf(XT[j * 128 + (row ^ SWZ(j))]);
            }
            a[rb][s] = av;
        }
    }

    constexpr int CPK = 128 / KSPLIT;
    const int c_lo = (kq == 0) ? 0 : (1 + kq * CPK);
    const int nc   = (kq == 0) ? (CPK + 1) : CPK;
    const __hip_bfloat16* wb = WB + (size_t)c_lo * WB_CHUNK + (size_t)(wn * 32 + cl) * IN + kg * 8;

    f32x4 y[4][2];
    #pragma unroll
    for (int rb = 0; rb < 4; ++rb)
        #pragma unroll
        for (int cb = 0; cb < 2; ++cb)
            y[rb][cb] = (f32x4){0.f, 0.f, 0.f, 0.f};

    bf16x8 B0[2][4], B1[2][4];

    auto loadB = [&](bf16x8 (&Bf)[2][4], int ci) {
        const __hip_bfloat16* p = wb + (size_t)ci * WB_CHUNK;
        #pragma unroll
        for (int cb = 0; cb < 2; ++cb)
            #pragma unroll
            for (int s = 0; s < 4; ++s)
                Bf[cb][s] = *(const bf16x8*)(p + cb * (16 * IN) + s * 32);
    };

    const f32x4 Zv = {0.f, 0.f, 0.f, 0.f};

    auto doChunk = [&](bf16x8 (&Bf)[2][4], int c) {
        f32x4 U[4][2];
        #pragma unroll
        for (int s = 0; s < 4; ++s)
            #pragma unroll
            for (int rb = 0; rb < 4; ++rb)
                #pragma unroll
                for (int cb = 0; cb < 2; ++cb)
                    U[rb][cb] = __builtin_amdgcn_mfma_f32_16x16x32_bf16(
                        a[rb][s], Bf[cb][s], (s == 0) ? Zv : U[rb][cb], 0, 0, 0);
        #pragma unroll
        for (int rb = 0; rb < 4; ++rb) {
            f32x4 xiv;
            if (c < 128) {
                const int rr = (wm * 64 + rb * 16 + kg * 4) ^ SWZ(c);
                xiv = *(const f32x4*)(&XT[c * 128 + rr]);
            } else {
                xiv = (f32x4){1.f, 1.f, 1.f, 1.f};
            }
            #pragma unroll
            for (int cb = 0; cb < 2; ++cb)
                #pragma unroll
                for (int q = 0; q < 4; ++q)
                    y[rb][cb][q] += xiv[q] * U[rb][cb][q];
        }
    };

    loadB(B0, 0);
    int ci = 0;
    for (;;) {
        if (ci + 1 < nc) loadB(B1, ci + 1);
        doChunk(B0, c_lo + ci);
        if (++ci >= nc) break;
        if (ci + 1 < nc) loadB(B0, ci + 1);
        doChunk(B1, c_lo + ci);
        if (++ci >= nc) break;
    }

    float* po = parts + (size_t)kq * ((size_t)NB * OUT);
    #pragma unroll
    for (int rb = 0; rb < 4; ++rb) {
        const int grow = row0 + wm * 64 + rb * 16 + kg * 4;
        #pragma unroll
        for (int cb = 0; cb < 2; ++cb) {
            const int col = wn * 32 + cb * 16 + cl;
            #pragma unroll
            for (int q = 0; q < 4; ++q)
                po[(size_t)(grow + q) * OUT + col] = y[rb][cb][q];
        }
    }
}

// ---- reduce split-K partials + bias, then LayerNorm(gamma, beta). One wave per row.
template<int KSPLIT>
__global__ __launch_bounds__(256) void reduce_ln(
    const float* __restrict__ parts, const float* __restrict__ bias,
    const float* __restrict__ gamma, const float* __restrict__ beta,
    float* __restrict__ out)
{
    const int lane = threadIdx.x & 63;
    const int row  = blockIdx.x * 4 + (threadIdx.x >> 6);
    const int c0   = lane * 2;
    const size_t off = (size_t)row * OUT + c0;
    const size_t Q = (size_t)NB * OUT;

    float2 bb = *(const float2*)(bias + c0);
    float y0 = bb.x, y1 = bb.y;
    #pragma unroll
    for (int k = 0; k < KSPLIT; ++k) {
        float2 p = *(const float2*)(parts + (size_t)k * Q + off);
        y0 += p.x; y1 += p.y;
    }

    float s = y0 + y1, ss = y0 * y0 + y1 * y1;
    #pragma unroll
    for (int m = 1; m < 64; m <<= 1) {
        s  += __shfl_xor(s, m);
        ss += __shfl_xor(ss, m);
    }
    const float mu  = s * (1.f / 128.f);
    const float var = ss * (1.f / 128.f) - mu * mu;
    const float rs  = rsqrtf(var + 1e-5f);

    float2 gg = *(const float2*)(gamma + c0);
    float2 be = *(const float2*)(beta + c0);
    float2 o2 = { (y0 - mu) * rs * gg.x + be.x, (y1 - mu) * rs * gg.y + be.y };
    *(float2*)(out + off) = o2;
}

extern "C" void kernel_launch(void* const* d_in, const int* in_sizes, int n_in,
                              void* d_out, int out_size, void* d_ws, size_t ws_size,
                              hipStream_t stream) {
    const float* x     = (const float*)d_in[0];
    const float* sc    = (const float*)d_in[1];
    const float* tr    = (const float*)d_in[2];
    const float* lcw   = (const float*)d_in[3];
    const float* w1    = (const float*)d_in[4];
    const float* gamma = (const float*)d_in[5];
    const float* beta  = (const float*)d_in[6];
    float* out = (float*)d_out;

    char* ws = (char*)d_ws;
    __hip_bfloat16* WB = (__hip_bfloat16*)ws;                       // 129*128*128*2 = 4,227,072 B
    float* bias  = (float*)(ws + 4227072);                          // 512 B
    float* parts = (float*)(ws + 4227072 + 512);                    // KSPLIT * 8192*128*4

    const size_t need8 = 4227072ull + 512ull + 8ull * NB * OUT * 4ull;

    prep_kernel<<<1033, 256, 0, stream>>>(lcw, w1, sc, tr, WB, bias);
    if (ws_size >= need8) {
        lc_gemm<8><<<512, 512, 0, stream>>>(x, sc, tr, WB, parts);
        reduce_ln<8><<<2048, 256, 0, stream>>>(parts, bias, gamma, beta, out);
    } else {
        lc_gemm<4><<<256, 512, 0, stream>>>(x, sc, tr, WB, parts);
        reduce_ln<4><<<2048, 256, 0, stream>>>(parts, bias, gamma, beta, out);
    }
}

// Round 4
// 171.830 us; speedup vs baseline: 2.2123x; 2.2123x over previous
//
#include <hip/hip_runtime.h>
#include <hip/hip_bf16.h>

typedef __attribute__((ext_vector_type(8))) short bf16x8;
typedef __attribute__((ext_vector_type(4))) float f32x4;

#define IN 128
#define OUT 128
#define NB 8192
#define NCH 129
#define WB_CHUNK (OUT * IN)           // 16384 elements per chunk
#define SWZ(j) ((((j) >> 2) & 7) << 2)

static __device__ __forceinline__ unsigned short f2bf(float v) {
    unsigned u = __builtin_bit_cast(unsigned, v);
    unsigned r = (u + 0x7FFFu + ((u >> 16) & 1u)) >> 16;   // RNE
    return (unsigned short)r;
}

// ---- prep: WB[129][o][j] bf16 (chunk i: lc_w[o,pos(i,j)], diag=0; chunk 128: w1*scale)
// ---- plus bias[o] = sum_j translation[j]*w1[o,j]
__global__ __launch_bounds__(256) void prep_kernel(
    const float* __restrict__ lcw, const float* __restrict__ w1,
    const float* __restrict__ sc, const float* __restrict__ tr,
    __hip_bfloat16* __restrict__ WB, float* __restrict__ bias)
{
    if (blockIdx.x < 1032) {
        size_t idx = (size_t)blockIdx.x * 2048 + (size_t)threadIdx.x * 8;
        int c   = (int)(idx >> 14);
        int rem = (int)(idx & 16383);
        int o   = rem >> 7;
        int j0  = rem & 127;
        bf16x8 v;
        if (c < 128) {
            const float* lr = lcw + (size_t)o * 16256 + (size_t)c * 127;
            #pragma unroll
            for (int e = 0; e < 8; ++e) {
                int j = j0 + e;
                float f = (j == c) ? 0.f : lr[(j < c) ? j : (j - 1)];
                v[e] = (short)f2bf(f);
            }
        } else {
            #pragma unroll
            for (int e = 0; e < 8; ++e) {
                int j = j0 + e;
                v[e] = (short)f2bf(w1[o * 128 + j] * sc[j]);
            }
        }
        *(bf16x8*)(WB + idx) = v;
    } else {
        // bias[o] = sum_j tr[j]*w1[o,j] — wave-parallel, coalesced 8B/lane
        const int lane = threadIdx.x & 63;
        const int wv   = threadIdx.x >> 6;         // 0..3
        const float2 t2 = *(const float2*)(tr + lane * 2);
        for (int o = wv; o < 128; o += 4) {
            const float2 w2 = *(const float2*)(w1 + o * 128 + lane * 2);
            float s = t2.x * w2.x + t2.y * w2.y;
            #pragma unroll
            for (int m = 1; m < 64; m <<= 1) s += __shfl_xor(s, m);
            if (lane == 0) bias[o] = s;
        }
    }
}

// ---- main GEMM: (64*KSPLIT) WGs (64 M-tiles x KSPLIT K-splits), 512 thr = 8 waves (2M x 4N)
// __launch_bounds__(512,2): VGPR budget 256 -> compiler lands at ~128, no spills
// (R2 lesson: (512,4) forced VGPR=64 -> 1.4 GB scratch spill traffic).
template<int KSPLIT>
__global__ __launch_bounds__(512, 2) void lc_gemm(
    const float* __restrict__ x, const float* __restrict__ sc, const float* __restrict__ tr,
    const __hip_bfloat16* __restrict__ WB, float* __restrict__ parts)
{
    __shared__ float XT[IN * 128];    // XT[j][row ^ SWZ(j)] = x_scaled, 64 KB

    const int tid = threadIdx.x;
    const int bid = blockIdx.x;
    const int mt  = bid / KSPLIT;
    const int kq  = bid % KSPLIT;     // == XCD id for KSPLIT=8
    const int row0 = mt << 7;

    {   // stage + transpose + scale/translate
        const int jj  = (tid & 31) << 2;
        const int swz = SWZ(jj);
        const float4 s4 = *(const float4*)(sc + jj);
        const float4 t4 = *(const float4*)(tr + jj);
        const float i0 = 1.f / s4.x, i1 = 1.f / s4.y, i2 = 1.f / s4.z, i3 = 1.f / s4.w;
        const int rb0 = tid >> 5;
        #pragma unroll
        for (int it = 0; it < 8; ++it) {
            const int r = rb0 + (it << 4);
            const float4 xv = *(const float4*)(x + (size_t)(row0 + r) * IN + jj);
            const int rs = r ^ swz;
            XT[(jj + 0) * 128 + rs] = (xv.x - t4.x) * i0;
            XT[(jj + 1) * 128 + rs] = (xv.y - t4.y) * i1;
            XT[(jj + 2) * 128 + rs] = (xv.z - t4.z) * i2;
            XT[(jj + 3) * 128 + rs] = (xv.w - t4.w) * i3;
        }
    }
    __syncthreads();

    const int lane = tid & 63;
    const int wv = tid >> 6;
    const int wm = wv >> 2;       // 0..1 : 64-row half
    const int wn = wv & 3;        // 0..3 : 32-col group
    const int cl = lane & 15;
    const int kg = lane >> 4;

    // A fragments: constant for the whole kernel (bf16 of scaled x)
    bf16x8 a[4][4];
    #pragma unroll
    for (int rb = 0; rb < 4; ++rb) {
        const int row = wm * 64 + rb * 16 + cl;
        #pragma unroll
        for (int s = 0; s < 4; ++s) {
            const int j0 = s * 32 + kg * 8;
            bf16x8 av;
            #pragma unroll
            for (int e = 0; e < 8; ++e) {
                const int j = j0 + e;
                av[e] = (short)f2bf(XT[j * 128 + (row ^ SWZ(j))]);
            }
            a[rb][s] = av;
        }
    }

    constexpr int CPK = 128 / KSPLIT;
    const int c_lo = (kq == 0) ? 0 : (1 + kq * CPK);
    const int nc   = (kq == 0) ? (CPK + 1) : CPK;
    const __hip_bfloat16* wb = WB + (size_t)c_lo * WB_CHUNK + (size_t)(wn * 32 + cl) * IN + kg * 8;

    f32x4 y[4][2];
    #pragma unroll
    for (int rb = 0; rb < 4; ++rb)
        #pragma unroll
        for (int cb = 0; cb < 2; ++cb)
            y[rb][cb] = (f32x4){0.f, 0.f, 0.f, 0.f};

    bf16x8 B0[2][4], B1[2][4];

    auto loadB = [&](bf16x8 (&Bf)[2][4], int ci) {
        const __hip_bfloat16* p = wb + (size_t)ci * WB_CHUNK;
        #pragma unroll
        for (int cb = 0; cb < 2; ++cb)
            #pragma unroll
            for (int s = 0; s < 4; ++s)
                Bf[cb][s] = *(const bf16x8*)(p + cb * (16 * IN) + s * 32);
    };

    const f32x4 Zv = {0.f, 0.f, 0.f, 0.f};

    auto doChunk = [&](bf16x8 (&Bf)[2][4], int c) {
        f32x4 U[4][2];
        #pragma unroll
        for (int s = 0; s < 4; ++s)
            #pragma unroll
            for (int rb = 0; rb < 4; ++rb)
                #pragma unroll
                for (int cb = 0; cb < 2; ++cb)
                    U[rb][cb] = __builtin_amdgcn_mfma_f32_16x16x32_bf16(
                        a[rb][s], Bf[cb][s], (s == 0) ? Zv : U[rb][cb], 0, 0, 0);
        #pragma unroll
        for (int rb = 0; rb < 4; ++rb) {
            f32x4 xiv;
            if (c < 128) {
                const int rr = (wm * 64 + rb * 16 + kg * 4) ^ SWZ(c);
                xiv = *(const f32x4*)(&XT[c * 128 + rr]);
            } else {
                xiv = (f32x4){1.f, 1.f, 1.f, 1.f};
            }
            #pragma unroll
            for (int cb = 0; cb < 2; ++cb)
                #pragma unroll
                for (int q = 0; q < 4; ++q)
                    y[rb][cb][q] += xiv[q] * U[rb][cb][q];
        }
    };

    loadB(B0, 0);
    int ci = 0;
    for (;;) {
        if (ci + 1 < nc) loadB(B1, ci + 1);
        doChunk(B0, c_lo + ci);
        if (++ci >= nc) break;
        if (ci + 1 < nc) loadB(B0, ci + 1);
        doChunk(B1, c_lo + ci);
        if (++ci >= nc) break;
    }

    float* po = parts + (size_t)kq * ((size_t)NB * OUT);
    #pragma unroll
    for (int rb = 0; rb < 4; ++rb) {
        const int grow = row0 + wm * 64 + rb * 16 + kg * 4;
        #pragma unroll
        for (int cb = 0; cb < 2; ++cb) {
            const int col = wn * 32 + cb * 16 + cl;
            #pragma unroll
            for (int q = 0; q < 4; ++q)
                po[(size_t)(grow + q) * OUT + col] = y[rb][cb][q];
        }
    }
}

// ---- reduce split-K partials + bias, then LayerNorm(gamma, beta). One wave per row.
template<int KSPLIT>
__global__ __launch_bounds__(256) void reduce_ln(
    const float* __restrict__ parts, const float* __restrict__ bias,
    const float* __restrict__ gamma, const float* __restrict__ beta,
    float* __restrict__ out)
{
    const int lane = threadIdx.x & 63;
    const int row  = blockIdx.x * 4 + (threadIdx.x >> 6);
    const int c0   = lane * 2;
    const size_t off = (size_t)row * OUT + c0;
    const size_t Q = (size_t)NB * OUT;

    float2 bb = *(const float2*)(bias + c0);
    float y0 = bb.x, y1 = bb.y;
    #pragma unroll
    for (int k = 0; k < KSPLIT; ++k) {
        float2 p = *(const float2*)(parts + (size_t)k * Q + off);
        y0 += p.x; y1 += p.y;
    }

    float s = y0 + y1, ss = y0 * y0 + y1 * y1;
    #pragma unroll
    for (int m = 1; m < 64; m <<= 1) {
        s  += __shfl_xor(s, m);
        ss += __shfl_xor(ss, m);
    }
    const float mu  = s * (1.f / 128.f);
    const float var = ss * (1.f / 128.f) - mu * mu;
    const float rs  = rsqrtf(var + 1e-5f);

    float2 gg = *(const float2*)(gamma + c0);
    float2 be = *(const float2*)(beta + c0);
    float2 o2 = { (y0 - mu) * rs * gg.x + be.x, (y1 - mu) * rs * gg.y + be.y };
    *(float2*)(out + off) = o2;
}

extern "C" void kernel_launch(void* const* d_in, const int* in_sizes, int n_in,
                              void* d_out, int out_size, void* d_ws, size_t ws_size,
                              hipStream_t stream) {
    const float* x     = (const float*)d_in[0];
    const float* sc    = (const float*)d_in[1];
    const float* tr    = (const float*)d_in[2];
    const float* lcw   = (const float*)d_in[3];
    const float* w1    = (const float*)d_in[4];
    const float* gamma = (const float*)d_in[5];
    const float* beta  = (const float*)d_in[6];
    float* out = (float*)d_out;

    char* ws = (char*)d_ws;
    __hip_bfloat16* WB = (__hip_bfloat16*)ws;                       // 129*128*128*2 = 4,227,072 B
    float* bias  = (float*)(ws + 4227072);                          // 512 B
    float* parts = (float*)(ws + 4227072 + 512);                    // KSPLIT * 8192*128*4

    const size_t need8 = 4227072ull + 512ull + 8ull * NB * OUT * 4ull;

    prep_kernel<<<1033, 256, 0, stream>>>(lcw, w1, sc, tr, WB, bias);
    if (ws_size >= need8) {
        lc_gemm<8><<<512, 512, 0, stream>>>(x, sc, tr, WB, parts);
        reduce_ln<8><<<2048, 256, 0, stream>>>(parts, bias, gamma, beta, out);
    } else {
        lc_gemm<4><<<256, 512, 0, stream>>>(x, sc, tr, WB, parts);
        reduce_ln<4><<<2048, 256, 0, stream>>>(parts, bias, gamma, beta, out);
    }
}

// Round 5
// 171.037 us; speedup vs baseline: 2.2225x; 1.0046x over previous
//
#include <hip/hip_runtime.h>
#include <hip/hip_bf16.h>

typedef _Float16 f16;
typedef __attribute__((ext_vector_type(8))) _Float16 f16x8;
typedef __attribute__((ext_vector_type(4))) float f32x4;

#define IN 128
#define OUT 128
#define NB 8192

// ws layout (bytes)
#define WB_OFF   0ull
#define WB_BYTES 4227072ull                  // 129*128*128*2
#define XH_OFF   4227072ull
#define XH_BYTES 2097152ull                  // 8192*128*2
#define BIAS_OFF 6324224ull
#define PARTS_OFF 6324736ull

// ---- prep: WB f16 [129][o][j] (chunk c<128: lc_w[o,pos(c,j)], diag 0; c=128: w1*scale),
// ---- xh f16 [8192][128] = (x - tr)/sc, bias[o] = sum_j tr[j]*w1[o,j]
__global__ __launch_bounds__(256) void prep_kernel(
    const float* __restrict__ x, const float* __restrict__ lcw, const float* __restrict__ w1,
    const float* __restrict__ sc, const float* __restrict__ tr,
    f16* __restrict__ WB, f16* __restrict__ xh, float* __restrict__ bias)
{
    const int bid = blockIdx.x;
    if (bid < 1032) {                          // WB: 129*16384 f16 elems
        size_t idx = (size_t)bid * 2048 + (size_t)threadIdx.x * 8;
        int c   = (int)(idx >> 14);
        int rem = (int)(idx & 16383);
        int o   = rem >> 7;
        int j0  = rem & 127;
        f16x8 v;
        if (c < 128) {
            const float* lr = lcw + (size_t)o * 16256 + (size_t)c * 127;
            #pragma unroll
            for (int e = 0; e < 8; ++e) {
                int j = j0 + e;
                float f = (j == c) ? 0.f : lr[(j < c) ? j : (j - 1)];
                v[e] = (f16)f;
            }
        } else {
            #pragma unroll
            for (int e = 0; e < 8; ++e) {
                int j = j0 + e;
                v[e] = (f16)(w1[o * 128 + j] * sc[j]);
            }
        }
        *(f16x8*)(WB + idx) = v;
    } else if (bid < 1544) {                   // xh: 1,048,576 elems
        size_t idx = (size_t)(bid - 1032) * 2048 + (size_t)threadIdx.x * 8;
        int j0 = (int)(idx & 127);
        const float4 x0 = *(const float4*)(x + idx);
        const float4 x1 = *(const float4*)(x + idx + 4);
        const float4 s0 = *(const float4*)(sc + j0);
        const float4 s1 = *(const float4*)(sc + j0 + 4);
        const float4 t0 = *(const float4*)(tr + j0);
        const float4 t1 = *(const float4*)(tr + j0 + 4);
        f16x8 v;
        v[0] = (f16)((x0.x - t0.x) / s0.x); v[1] = (f16)((x0.y - t0.y) / s0.y);
        v[2] = (f16)((x0.z - t0.z) / s0.z); v[3] = (f16)((x0.w - t0.w) / s0.w);
        v[4] = (f16)((x1.x - t1.x) / s1.x); v[5] = (f16)((x1.y - t1.y) / s1.y);
        v[6] = (f16)((x1.z - t1.z) / s1.z); v[7] = (f16)((x1.w - t1.w) / s1.w);
        *(f16x8*)(xh + idx) = v;
    } else {                                   // bias
        const int lane = threadIdx.x & 63;
        const int wv   = threadIdx.x >> 6;
        const float2 t2 = *(const float2*)(tr + lane * 2);
        for (int o = wv; o < 128; o += 4) {
            const float2 w2 = *(const float2*)(w1 + o * 128 + lane * 2);
            float s = t2.x * w2.x + t2.y * w2.y;
            #pragma unroll
            for (int m = 1; m < 64; m <<= 1) s += __shfl_xor(s, m);
            if (lane == 0) bias[o] = s;
        }
    }
}

// ---- main: y[b,o] = sum_c xs[b,c] * (Xs @ W_c^T)[b,o], A generated in-register via pk_mul.
// B chunks staged to LDS via global_load_lds with pre-swizzled source (XOR bits 4-6 by row&7).
template<int KSPLIT>
__global__ __launch_bounds__(512, 2) void lc_gemm(
    const f16* __restrict__ xh, const f16* __restrict__ WB, float* __restrict__ parts)
{
    __shared__ f16 Bb[2][16384];               // 2 x 32 KB double buffer

    const int tid = threadIdx.x;
    const int bid = blockIdx.x;
    const int mt  = bid / KSPLIT;
    const int kq  = bid % KSPLIT;              // == XCD id (mod) for KSPLIT=8
    const int row0 = mt << 7;

    const int lane = tid & 63;
    const int wv   = tid >> 6;
    const int wm   = wv >> 2;                  // 0..1 : 64-row half
    const int wn   = wv & 3;                   // 0..3 : 32-col group
    const int cl   = lane & 15;
    const int kg   = lane >> 4;

    // ---- A-base fragments from global xh (f16 scaled x), rows fixed per lane
    size_t rwb[4];
    #pragma unroll
    for (int rb = 0; rb < 4; ++rb)
        rwb[rb] = (size_t)(row0 + wm * 64 + rb * 16 + cl) * IN;

    f16x8 ab[4][4];
    #pragma unroll
    for (int rb = 0; rb < 4; ++rb)
        #pragma unroll
        for (int s = 0; s < 4; ++s)
            ab[rb][s] = *(const f16x8*)(xh + rwb[rb] + s * 32 + kg * 8);

    // ---- DMA source offsets (pre-swizzled) and fragment read offsets
    int dmac[4];
    #pragma unroll
    for (int p = 0; p < 4; ++p) {
        int L = ((p * 8 + wv) << 10) + (lane << 4);
        dmac[p] = L ^ (((L >> 8) & 7) << 4);
    }
    int boff[2][4];
    #pragma unroll
    for (int cb = 0; cb < 2; ++cb)
        #pragma unroll
        for (int s = 0; s < 4; ++s) {
            int o = wn * 32 + cb * 16 + cl;
            int b = (o << 8) + ((s * 32 + kg * 8) << 1);
            boff[cb][s] = b ^ ((o & 7) << 4);
        }

    constexpr int CPK = 128 / KSPLIT;
    const int c_lo = (kq == 0) ? 0 : (1 + kq * CPK);
    const int nc   = (kq == 0) ? (CPK + 1) : CPK;

    auto stageB = [&](int c, int buf) {
        const char* src = (const char*)WB + (size_t)c * 32768;
        char* dstb = (char*)(&Bb[0][0]) + (buf << 15);
        #pragma unroll
        for (int p = 0; p < 4; ++p) {
            __builtin_amdgcn_global_load_lds(
                (const __attribute__((address_space(1))) unsigned int*)(src + dmac[p]),
                (__attribute__((address_space(3))) unsigned int*)(dstb + ((p * 8 + wv) << 10)),
                16, 0, 0);
        }
    };

    f32x4 acc[4][2];
    #pragma unroll
    for (int rb = 0; rb < 4; ++rb)
        #pragma unroll
        for (int cb = 0; cb < 2; ++cb)
            acc[rb][cb] = (f32x4){0.f, 0.f, 0.f, 0.f};

    stageB(c_lo, 0);
    __syncthreads();                            // drains vmcnt(0): chunk 0 in LDS

    int cur = 0;
    for (int ci = 0; ci < nc; ++ci) {
        const int c = c_lo + ci;
        if (ci + 1 < nc) stageB(c + 1, cur ^ 1);

        // per-lane row scalars xs[row][c]  (c==128 -> 1.0: base term)
        f16 xs[4];
        if (c < 128) {
            #pragma unroll
            for (int rb = 0; rb < 4; ++rb) xs[rb] = xh[rwb[rb] + c];
        } else {
            #pragma unroll
            for (int rb = 0; rb < 4; ++rb) xs[rb] = (f16)1.0f;
        }

        // B fragments from LDS (swizzled, conflict-free-ish)
        f16x8 bf[2][4];
        const char* bbase = (const char*)(&Bb[0][0]) + (cur << 15);
        #pragma unroll
        for (int cb = 0; cb < 2; ++cb)
            #pragma unroll
            for (int s = 0; s < 4; ++s)
                bf[cb][s] = *(const f16x8*)(bbase + boff[cb][s]);

        // MFMA with on-the-fly A generation (4 pk_mul each)
        #pragma unroll
        for (int s = 0; s < 4; ++s)
            #pragma unroll
            for (int rb = 0; rb < 4; ++rb) {
                f16x8 xbv;
                #pragma unroll
                for (int e = 0; e < 8; ++e) xbv[e] = xs[rb];
                f16x8 af = ab[rb][s] * xbv;
                #pragma unroll
                for (int cb = 0; cb < 2; ++cb)
                    acc[rb][cb] = __builtin_amdgcn_mfma_f32_16x16x32_f16(
                        af, bf[cb][s], acc[rb][cb], 0, 0, 0);
            }

        __syncthreads();                        // drains next-chunk DMA + releases cur
        cur ^= 1;
    }

    float* po = parts + (size_t)kq * ((size_t)NB * OUT);
    #pragma unroll
    for (int rb = 0; rb < 4; ++rb) {
        const int grow = row0 + wm * 64 + rb * 16 + kg * 4;
        #pragma unroll
        for (int cb = 0; cb < 2; ++cb) {
            const int col = wn * 32 + cb * 16 + cl;
            #pragma unroll
            for (int q = 0; q < 4; ++q)
                po[(size_t)(grow + q) * OUT + col] = acc[rb][cb][q];
        }
    }
}

// ---- reduce split-K partials + bias, then LayerNorm. One wave per row.
template<int KSPLIT>
__global__ __launch_bounds__(256) void reduce_ln(
    const float* __restrict__ parts, const float* __restrict__ bias,
    const float* __restrict__ gamma, const float* __restrict__ beta,
    float* __restrict__ out)
{
    const int lane = threadIdx.x & 63;
    const int row  = blockIdx.x * 4 + (threadIdx.x >> 6);
    const int c0   = lane * 2;
    const size_t off = (size_t)row * OUT + c0;
    const size_t Q = (size_t)NB * OUT;

    float2 bb = *(const float2*)(bias + c0);
    float y0 = bb.x, y1 = bb.y;
    #pragma unroll
    for (int k = 0; k < KSPLIT; ++k) {
        float2 p = *(const float2*)(parts + (size_t)k * Q + off);
        y0 += p.x; y1 += p.y;
    }

    float s = y0 + y1, ss = y0 * y0 + y1 * y1;
    #pragma unroll
    for (int m = 1; m < 64; m <<= 1) {
        s  += __shfl_xor(s, m);
        ss += __shfl_xor(ss, m);
    }
    const float mu  = s * (1.f / 128.f);
    const float var = ss * (1.f / 128.f) - mu * mu;
    const float rs  = rsqrtf(var + 1e-5f);

    float2 gg = *(const float2*)(gamma + c0);
    float2 be = *(const float2*)(beta + c0);
    float2 o2 = { (y0 - mu) * rs * gg.x + be.x, (y1 - mu) * rs * gg.y + be.y };
    *(float2*)(out + off) = o2;
}

extern "C" void kernel_launch(void* const* d_in, const int* in_sizes, int n_in,
                              void* d_out, int out_size, void* d_ws, size_t ws_size,
                              hipStream_t stream) {
    const float* x     = (const float*)d_in[0];
    const float* sc    = (const float*)d_in[1];
    const float* tr    = (const float*)d_in[2];
    const float* lcw   = (const float*)d_in[3];
    const float* w1    = (const float*)d_in[4];
    const float* gamma = (const float*)d_in[5];
    const float* beta  = (const float*)d_in[6];
    float* out = (float*)d_out;

    char* ws = (char*)d_ws;
    f16*   WB    = (f16*)(ws + WB_OFF);
    f16*   xh    = (f16*)(ws + XH_OFF);
    float* bias  = (float*)(ws + BIAS_OFF);
    float* parts = (float*)(ws + PARTS_OFF);

    const size_t need8 = PARTS_OFF + 8ull * NB * OUT * 4ull;   // ~39.9 MB

    prep_kernel<<<1545, 256, 0, stream>>>(x, lcw, w1, sc, tr, WB, xh, bias);
    if (ws_size >= need8) {
        lc_gemm<8><<<512, 512, 0, stream>>>(xh, WB, parts);
        reduce_ln<8><<<2048, 256, 0, stream>>>(parts, bias, gamma, beta, out);
    } else {
        lc_gemm<4><<<256, 512, 0, stream>>>(xh, WB, parts);
        reduce_ln<4><<<2048, 256, 0, stream>>>(parts, bias, gamma, beta, out);
    }
}

// Round 6
// 134.450 us; speedup vs baseline: 2.8273x; 1.2721x over previous
//
#include <hip/hip_runtime.h>
#include <hip/hip_bf16.h>

typedef _Float16 f16;
typedef __attribute__((ext_vector_type(8))) _Float16 f16x8;
typedef __attribute__((ext_vector_type(4))) float f32x4;

#define IN 128
#define OUT 128
#define NB 8192
#define CPK 32                       // chunks per kq (kq=0 gets +1)

// ws layout (bytes)
#define WB_OFF   0ull
#define XH_OFF   4227072ull          // 129*128*128*2
#define BIAS_OFF 6324224ull          // + 8192*128*2
#define PARTS_OFF 6324736ull         // + 512

// ---- prep: WB f16 [129][o][j] (c<128: lc_w[o,pos(c,j)], diag 0; c=128: w1*scale),
// ---- xh f16 = (x - tr)/sc, bias[o] = sum_j tr[j]*w1[o,j]
__global__ __launch_bounds__(256) void prep_kernel(
    const float* __restrict__ x, const float* __restrict__ lcw, const float* __restrict__ w1,
    const float* __restrict__ sc, const float* __restrict__ tr,
    f16* __restrict__ WB, f16* __restrict__ xh, float* __restrict__ bias)
{
    const int bid = blockIdx.x;
    if (bid < 1032) {                          // WB: 129*16384 f16 elems
        size_t idx = (size_t)bid * 2048 + (size_t)threadIdx.x * 8;
        int c   = (int)(idx >> 14);
        int rem = (int)(idx & 16383);
        int o   = rem >> 7;
        int j0  = rem & 127;
        f16x8 v;
        if (c < 128) {
            const float* lr = lcw + (size_t)o * 16256 + (size_t)c * 127;
            #pragma unroll
            for (int e = 0; e < 8; ++e) {
                int j = j0 + e;
                float f = (j == c) ? 0.f : lr[(j < c) ? j : (j - 1)];
                v[e] = (f16)f;
            }
        } else {
            #pragma unroll
            for (int e = 0; e < 8; ++e) {
                int j = j0 + e;
                v[e] = (f16)(w1[o * 128 + j] * sc[j]);
            }
        }
        *(f16x8*)(WB + idx) = v;
    } else if (bid < 1544) {                   // xh
        size_t idx = (size_t)(bid - 1032) * 2048 + (size_t)threadIdx.x * 8;
        int j0 = (int)(idx & 127);
        const float4 x0 = *(const float4*)(x + idx);
        const float4 x1 = *(const float4*)(x + idx + 4);
        const float4 s0 = *(const float4*)(sc + j0);
        const float4 s1 = *(const float4*)(sc + j0 + 4);
        const float4 t0 = *(const float4*)(tr + j0);
        const float4 t1 = *(const float4*)(tr + j0 + 4);
        f16x8 v;
        v[0] = (f16)((x0.x - t0.x) / s0.x); v[1] = (f16)((x0.y - t0.y) / s0.y);
        v[2] = (f16)((x0.z - t0.z) / s0.z); v[3] = (f16)((x0.w - t0.w) / s0.w);
        v[4] = (f16)((x1.x - t1.x) / s1.x); v[5] = (f16)((x1.y - t1.y) / s1.y);
        v[6] = (f16)((x1.z - t1.z) / s1.z); v[7] = (f16)((x1.w - t1.w) / s1.w);
        *(f16x8*)(xh + idx) = v;
    } else {                                   // bias
        const int lane = threadIdx.x & 63;
        const int wv   = threadIdx.x >> 6;
        const float2 t2 = *(const float2*)(tr + lane * 2);
        for (int o = wv; o < 128; o += 4) {
            const float2 w2 = *(const float2*)(w1 + o * 128 + lane * 2);
            float s = t2.x * w2.x + t2.y * w2.y;
            #pragma unroll
            for (int m = 1; m < 64; m <<= 1) s += __shfl_xor(s, m);
            if (lane == 0) bias[o] = s;
        }
    }
}

// ---- main: 256 WGs (64 M-tiles x 4 K-splits), 512 thr = 8 waves (2M x 4N), 1 block/CU.
// In-reg A (asm keep-alive), LDS B double-buffer via global_load_lds (pre-swizzled src),
// counted-vmcnt 2-deep pipeline with raw s_barrier (never vmcnt(0) mid-loop).
__global__ __launch_bounds__(512, 1) void lc_gemm(
    const f16* __restrict__ xh, const f16* __restrict__ WB, float* __restrict__ parts)
{
    __shared__ f16 Bb[2][16384];               // 2 x 32 KB
    __shared__ f16 xls[33 * 128];              // per-block x column slice

    const int tid = threadIdx.x;
    const int bid = blockIdx.x;
    const int mt  = bid >> 2;
    const int kq  = bid & 3;
    const int row0 = mt << 7;

    const int lane = tid & 63;
    const int wv   = tid >> 6;
    const int wm   = wv >> 2;                  // 0..1 : 64-row half
    const int wn   = wv & 3;                   // 0..3 : 32-col group
    const int cl   = lane & 15;
    const int kg   = lane >> 4;

    const int c_lo = (kq == 0) ? 0 : (1 + kq * CPK);

    // ---- A-base fragments, resident whole kernel
    f16x8 ab[4][4];
    #pragma unroll
    for (int rb = 0; rb < 4; ++rb) {
        const size_t rw = (size_t)(row0 + wm * 64 + rb * 16 + cl) * IN;
        #pragma unroll
        for (int s = 0; s < 4; ++s)
            ab[rb][s] = *(const f16x8*)(xh + rw + s * 32 + kg * 8);
    }
    #pragma unroll
    for (int rb = 0; rb < 4; ++rb)
        #pragma unroll
        for (int s = 0; s < 4; ++s)
            asm volatile("" : "+v"(ab[rb][s]));      // pin: no remat/sink

    // ---- DMA source offsets (pre-swizzled: bits4-7 ^= o&15) + LDS read offsets
    int dmac[4];
    #pragma unroll
    for (int p = 0; p < 4; ++p) {
        int L = ((p * 8 + wv) << 10) | (lane << 4);
        dmac[p] = L ^ (((L >> 8) & 15) << 4);
    }
    int boff[2][4];
    #pragma unroll
    for (int cb = 0; cb < 2; ++cb)
        #pragma unroll
        for (int s = 0; s < 4; ++s) {
            int o = wn * 32 + cb * 16 + cl;
            boff[cb][s] = (o << 8) + ((((s << 2) + kg) ^ (o & 15)) << 4);
        }

    auto stageB = [&](int c, int buf) {
        const char* src = (const char*)WB + ((size_t)c << 15);
        #pragma unroll
        for (int p = 0; p < 4; ++p) {
            __builtin_amdgcn_global_load_lds(
                (const __attribute__((address_space(1))) unsigned int*)(src + dmac[p]),
                (__attribute__((address_space(3))) unsigned int*)((char*)(&Bb[buf][0]) + ((p * 8 + wv) << 10)),
                16, 0, 0);
        }
    };

    f32x4 acc[4][2];
    #pragma unroll
    for (int rb = 0; rb < 4; ++rb)
        #pragma unroll
        for (int cb = 0; cb < 2; ++cb)
            acc[rb][cb] = (f32x4){0.f, 0.f, 0.f, 0.f};

#define KLOOP(NCV)                                                              \
    {                                                                           \
        constexpr int NC = NCV;                                                 \
        for (int pass = 0; pass < (NC + 3) / 4; ++pass) {                       \
            int cp = pass * 4 + (tid >> 7);                                     \
            if (cp < NC) {                                                      \
                int c = c_lo + cp;                                              \
                f16 v = (c < 128)                                               \
                    ? xh[(size_t)(row0 + (tid & 127)) * IN + c]                 \
                    : (f16)1.0f;                                                \
                xls[cp * 128 + (tid & 127)] = v;                                \
            }                                                                   \
        }                                                                       \
        stageB(c_lo + 0, 0);                                                    \
        stageB(c_lo + 1, 1);                                                    \
        __syncthreads();                                                        \
        _Pragma("unroll")                                                       \
        for (int ci = 0; ci < NC; ++ci) {                                       \
            if (ci >= 2) {                                                      \
                if (ci + 1 < NC) asm volatile("s_waitcnt vmcnt(4)" ::: "memory");\
                else             asm volatile("s_waitcnt vmcnt(0)" ::: "memory");\
                __builtin_amdgcn_s_barrier();                                   \
                __builtin_amdgcn_sched_barrier(0);                              \
            }                                                                   \
            const char* bbase = (const char*)(&Bb[ci & 1][0]);                  \
            f16x8 bf[2][4];                                                     \
            _Pragma("unroll")                                                   \
            for (int cb = 0; cb < 2; ++cb)                                      \
                _Pragma("unroll")                                               \
                for (int s = 0; s < 4; ++s)                                     \
                    bf[cb][s] = *(const f16x8*)(bbase + boff[cb][s]);           \
            f16 xs[4];                                                          \
            _Pragma("unroll")                                                   \
            for (int rb = 0; rb < 4; ++rb)                                      \
                xs[rb] = xls[ci * 128 + wm * 64 + rb * 16 + cl];                \
            _Pragma("unroll")                                                   \
            for (int s = 0; s < 4; ++s)                                         \
                _Pragma("unroll")                                               \
                for (int rb = 0; rb < 4; ++rb) {                                \
                    f16x8 xbv;                                                  \
                    _Pragma("unroll")                                           \
                    for (int e = 0; e < 8; ++e) xbv[e] = xs[rb];                \
                    f16x8 af = ab[rb][s] * xbv;                                 \
                    _Pragma("unroll")                                           \
                    for (int cb = 0; cb < 2; ++cb)                              \
                        acc[rb][cb] = __builtin_amdgcn_mfma_f32_16x16x32_f16(   \
                            af, bf[cb][s], acc[rb][cb], 0, 0, 0);               \
                }                                                               \
            __builtin_amdgcn_sched_barrier(0);                                  \
            __builtin_amdgcn_s_barrier();                                       \
            __builtin_amdgcn_sched_barrier(0);                                  \
            if (ci + 2 < NC) stageB(c_lo + ci + 2, ci & 1);                     \
        }                                                                       \
    }

    if (kq == 0) KLOOP(CPK + 1) else KLOOP(CPK)
#undef KLOOP

    float* po = parts + (size_t)kq * ((size_t)NB * OUT);
    #pragma unroll
    for (int rb = 0; rb < 4; ++rb) {
        const int grow = row0 + wm * 64 + rb * 16 + kg * 4;
        #pragma unroll
        for (int cb = 0; cb < 2; ++cb) {
            const int col = wn * 32 + cb * 16 + cl;
            #pragma unroll
            for (int q = 0; q < 4; ++q)
                po[(size_t)(grow + q) * OUT + col] = acc[rb][cb][q];
        }
    }
}

// ---- reduce 4 split-K partials + bias, then LayerNorm. One wave per row.
__global__ __launch_bounds__(256) void reduce_ln(
    const float* __restrict__ parts, const float* __restrict__ bias,
    const float* __restrict__ gamma, const float* __restrict__ beta,
    float* __restrict__ out)
{
    const int lane = threadIdx.x & 63;
    const int row  = blockIdx.x * 4 + (threadIdx.x >> 6);
    const int c0   = lane * 2;
    const size_t off = (size_t)row * OUT + c0;
    const size_t Q = (size_t)NB * OUT;

    float2 bb = *(const float2*)(bias + c0);
    float2 p0 = *(const float2*)(parts + off);
    float2 p1 = *(const float2*)(parts + Q + off);
    float2 p2 = *(const float2*)(parts + 2 * Q + off);
    float2 p3 = *(const float2*)(parts + 3 * Q + off);
    float y0 = bb.x + p0.x + p1.x + p2.x + p3.x;
    float y1 = bb.y + p0.y + p1.y + p2.y + p3.y;

    float s = y0 + y1, ss = y0 * y0 + y1 * y1;
    #pragma unroll
    for (int m = 1; m < 64; m <<= 1) {
        s  += __shfl_xor(s, m);
        ss += __shfl_xor(ss, m);
    }
    const float mu  = s * (1.f / 128.f);
    const float var = ss * (1.f / 128.f) - mu * mu;
    const float rs  = rsqrtf(var + 1e-5f);

    float2 gg = *(const float2*)(gamma + c0);
    float2 be = *(const float2*)(beta + c0);
    float2 o2 = { (y0 - mu) * rs * gg.x + be.x, (y1 - mu) * rs * gg.y + be.y };
    *(float2*)(out + off) = o2;
}

extern "C" void kernel_launch(void* const* d_in, const int* in_sizes, int n_in,
                              void* d_out, int out_size, void* d_ws, size_t ws_size,
                              hipStream_t stream) {
    const float* x     = (const float*)d_in[0];
    const float* sc    = (const float*)d_in[1];
    const float* tr    = (const float*)d_in[2];
    const float* lcw   = (const float*)d_in[3];
    const float* w1    = (const float*)d_in[4];
    const float* gamma = (const float*)d_in[5];
    const float* beta  = (const float*)d_in[6];
    float* out = (float*)d_out;

    char* ws = (char*)d_ws;
    f16*   WB    = (f16*)(ws + WB_OFF);
    f16*   xh    = (f16*)(ws + XH_OFF);
    float* bias  = (float*)(ws + BIAS_OFF);
    float* parts = (float*)(ws + PARTS_OFF);

    prep_kernel<<<1545, 256, 0, stream>>>(x, lcw, w1, sc, tr, WB, xh, bias);
    lc_gemm<<<256, 512, 0, stream>>>(xh, WB, parts);
    reduce_ln<<<2048, 256, 0, stream>>>(parts, bias, gamma, beta, out);
}